// Round 18
// baseline (741.913 us; speedup 1.0000x reference)
//
#include <hip/hip_runtime.h>
#include <hip/hip_cooperative_groups.h>

namespace cg = cooperative_groups;

// Exact-arithmetic replication of the JAX reference: no FMA contraction.
#pragma clang fp contract(off)

#define KK 12
#define EPS_Z 0.001f
#define BIG 1.0e10f

// JAX linspace(0,1,12): delta = f32(1/11) (one rounded division), t_k = k*delta.
#define T_DELTA (1.0f / 11.0f)

// "Empty" sentinel: max uint in mapped order; any real depth beats it.
#define Z_EMPTY 0xFFFFFFFFu

// Order-preserving float -> uint mapping (monotone for all finite floats,
// including negatives), so atomicMin(uint) == float min.
__device__ __forceinline__ unsigned int fmap(float f) {
    unsigned int u = __float_as_uint(f);
    return (u & 0x80000000u) ? ~u : (u | 0x80000000u);
}
__device__ __forceinline__ float funmap(unsigned int u) {
    return (u & 0x80000000u) ? __uint_as_float(u ^ 0x80000000u)
                             : __uint_as_float(~u);
}

// Workspace layout: ws[0 .. HW) = zbuf, ws[HW .. HW + HW/32) = live-pixel mask.
// use_mask is a pure function of (ws_size, HW) -> uniform across the grid.
__device__ __forceinline__ bool use_mask_for(unsigned long long ws_size, int HW) {
    return ws_size >= (unsigned long long)HW * 4ull + (unsigned long long)(HW / 8);
}

// ---------------- Fused cooperative kernel (4 phases) ----------------
__global__ void __launch_bounds__(256, 8)
fused(const float* __restrict__ verts, const int* __restrict__ tris,
      int N, int T, const int* __restrict__ pH, const int* __restrict__ pW,
      unsigned int* ws, unsigned long long ws_size, float* __restrict__ out) {
#pragma clang fp contract(off)
    cg::grid_group grid = cg::this_grid();
    const int W = pW[0];
    const int H = pH[0];
    const int HW = W * H;
    const bool um = use_mask_for(ws_size, HW);
    unsigned int* zbuf = ws;
    unsigned int* mask = ws + HW;
    const float Wm1 = (float)(W - 1);
    const float Hm1 = (float)(H - 1);
    const int tid = blockIdx.x * blockDim.x + threadIdx.x;
    const int nthr = gridDim.x * blockDim.x;

    // ---- Phase 1: init zbuf + mask ----
    {
        int total = HW + (um ? HW / 32 : 0);
        for (int idx = tid; idx < total; idx += nthr)
            ws[idx] = (idx < HW) ? Z_EMPTY : 0u;
    }
    grid.sync();

    // ---- Phase 2: mark live pixels (same ix/iy math as phase 4) ----
    if (um) {
        for (int n = tid; n < N; n += nthr) {
            float x = verts[n * 3 + 0], y = verts[n * 3 + 1];
            if ((x >= 0.0f) && (x <= Wm1) && (y >= 0.0f) && (y <= Hm1)) {
                int ix = (int)fminf(fmaxf(rintf(x), 0.0f), Wm1);
                int iy = (int)fminf(fmaxf(rintf(y), 0.0f), Hm1);
                int idx = iy * W + ix;
                atomicOr(&mask[idx >> 5], 1u << (idx & 31));
            }
        }
    }
    grid.sync();

    // ---- Phase 3: raster (work item = (i, t); i = px column sample) ----
    {
        int total = T * KK;
        for (int wk = tid; wk < total; wk += nthr) {
            int t = wk % T;
            int i = wk / T;

            int i0 = tris[t * 3 + 0], i1 = tris[t * 3 + 1], i2 = tris[t * 3 + 2];
            float x0 = verts[i0 * 3 + 0], y0 = verts[i0 * 3 + 1], z0 = verts[i0 * 3 + 2];
            float x1 = verts[i1 * 3 + 0], y1 = verts[i1 * 3 + 1], z1 = verts[i1 * 3 + 2];
            float x2 = verts[i2 * 3 + 0], y2 = verts[i2 * 3 + 1], z2 = verts[i2 * 3 + 2];

            float area = (x2 - x0) * (y1 - y0) - (y2 - y0) * (x1 - x0);
            if (!(fabsf(area) > 1e-8f)) continue;  // invalid -> BIG -> no-op

            float xmin = fminf(x0, fminf(x1, x2));
            float xmax = fmaxf(x0, fmaxf(x1, x2));
            float ymin = fminf(y0, fminf(y1, y2));
            float ymax = fmaxf(y0, fmaxf(y1, y2));

            // t_i = f32(i) * f32(1/11)  — matches jnp.linspace exactly.
            float ti = (float)i * T_DELTA;
            float px = xmin + ti * (xmax - xmin);
            if (!(px >= 0.0f && px <= Wm1)) continue;  // whole column off-image

            int ix = (int)fminf(fmaxf(rintf(px), 0.0f), Wm1);

            float e0dy = y2 - y1, e0dx = x2 - x1;  // edge(v1,v2)
            float e1dy = y0 - y2, e1dx = x0 - x2;  // edge(v2,v0)
            float e2dy = y1 - y0, e2dx = x1 - x0;  // edge(v0,v1)
            float a0 = (px - x1) * e0dy;
            float a1 = (px - x2) * e1dy;
            float a2 = (px - x0) * e2dy;

            float dy = ymax - ymin;
#pragma unroll
            for (int j = 0; j < KK; ++j) {
                float tj = (float)j * T_DELTA;  // compile-time, matches linspace
                float py = ymin + tj * dy;
                if (!(py >= 0.0f && py <= Hm1)) continue;
                float w0 = a0 - (py - y1) * e0dx;
                float w1 = a1 - (py - y2) * e1dx;
                float w2 = a2 - (py - y0) * e2dx;
                bool inside = (w0 >= 0.0f && w1 >= 0.0f && w2 >= 0.0f) ||
                              (w0 <= 0.0f && w1 <= 0.0f && w2 <= 0.0f);
                if (!inside) continue;
                float depth = ((w0 * z0 + w1 * z1) + w2 * z2) / area;  // left-assoc
                int iy = (int)fminf(fmaxf(rintf(py), 0.0f), Hm1);
                int idx = iy * W + ix;
                if (um) {
                    unsigned int mw = mask[idx >> 5];          // cached RO load
                    if (!((mw >> (idx & 31)) & 1u)) continue;  // dead pixel
                }
                atomicMin(&zbuf[idx], fmap(depth));
            }
        }
    }
    grid.sync();

    // ---- Phase 4: visibility ----
    for (int n = tid; n < N; n += nthr) {
        float x = verts[n * 3 + 0], y = verts[n * 3 + 1], z = verts[n * 3 + 2];
        bool in_img = (x >= 0.0f) && (x <= Wm1) && (y >= 0.0f) && (y <= Hm1);
        float r = 0.0f;
        if (in_img) {
            int ix = (int)fminf(fmaxf(rintf(x), 0.0f), Wm1);
            int iy = (int)fminf(fmaxf(rintf(y), 0.0f), Hm1);
            unsigned int u = zbuf[iy * W + ix];
            float zb = (u == Z_EMPTY) ? BIG : funmap(u);
            r = (z <= zb + EPS_Z) ? 1.0f : 0.0f;
        }
        out[n] = r;
    }
}

// ---------------- Fallback: proven round-13 4-dispatch path ----------------
__global__ void init_ws(unsigned int* __restrict__ ws,
                        const int* __restrict__ pH, const int* __restrict__ pW,
                        unsigned long long ws_size) {
    int HW = pH[0] * pW[0];
    bool um = use_mask_for(ws_size, HW);
    long long total = HW + (um ? HW / 32 : 0);
    for (long long i = blockIdx.x * (long long)blockDim.x + threadIdx.x; i < total;
         i += (long long)gridDim.x * blockDim.x)
        ws[i] = (i < HW) ? Z_EMPTY : 0u;
}

__global__ void mark_live(const float* __restrict__ verts, int N,
                          const int* __restrict__ pH, const int* __restrict__ pW,
                          unsigned int* __restrict__ ws,
                          unsigned long long ws_size) {
#pragma clang fp contract(off)
    const int W = pW[0];
    const int HW = W * pH[0];
    if (!use_mask_for(ws_size, HW)) return;
    unsigned int* mask = ws + HW;
    int n = blockIdx.x * blockDim.x + threadIdx.x;
    if (n >= N) return;
    const float Wm1 = (float)(W - 1);
    const float Hm1 = (float)(pH[0] - 1);
    float x = verts[n * 3 + 0], y = verts[n * 3 + 1];
    if ((x >= 0.0f) && (x <= Wm1) && (y >= 0.0f) && (y <= Hm1)) {
        int ix = (int)fminf(fmaxf(rintf(x), 0.0f), Wm1);
        int iy = (int)fminf(fmaxf(rintf(y), 0.0f), Hm1);
        int idx = iy * W + ix;
        atomicOr(&mask[idx >> 5], 1u << (idx & 31));
    }
}

__global__ void raster(const float* __restrict__ verts, const int* __restrict__ tris,
                       int T, const int* __restrict__ pH, const int* __restrict__ pW,
                       unsigned int* ws, unsigned long long ws_size) {
#pragma clang fp contract(off)
    int t = blockIdx.x * blockDim.x + threadIdx.x;
    if (t >= T) return;
    const int i = blockIdx.y;
    const int W = pW[0];
    const int H = pH[0];
    const int HW = W * H;
    const bool um = use_mask_for(ws_size, HW);
    unsigned int* zbuf = ws;
    const unsigned int* mask = ws + HW;
    const float Wm1 = (float)(W - 1);
    const float Hm1 = (float)(H - 1);

    int i0 = tris[t * 3 + 0], i1 = tris[t * 3 + 1], i2 = tris[t * 3 + 2];
    float x0 = verts[i0 * 3 + 0], y0 = verts[i0 * 3 + 1], z0 = verts[i0 * 3 + 2];
    float x1 = verts[i1 * 3 + 0], y1 = verts[i1 * 3 + 1], z1 = verts[i1 * 3 + 2];
    float x2 = verts[i2 * 3 + 0], y2 = verts[i2 * 3 + 1], z2 = verts[i2 * 3 + 2];

    float area = (x2 - x0) * (y1 - y0) - (y2 - y0) * (x1 - x0);
    if (!(fabsf(area) > 1e-8f)) return;

    float xmin = fminf(x0, fminf(x1, x2));
    float xmax = fmaxf(x0, fmaxf(x1, x2));
    float ymin = fminf(y0, fminf(y1, y2));
    float ymax = fmaxf(y0, fmaxf(y1, y2));

    float ti = (float)i * T_DELTA;
    float px = xmin + ti * (xmax - xmin);
    if (!(px >= 0.0f && px <= Wm1)) return;

    int ix = (int)fminf(fmaxf(rintf(px), 0.0f), Wm1);

    float e0dy = y2 - y1, e0dx = x2 - x1;
    float e1dy = y0 - y2, e1dx = x0 - x2;
    float e2dy = y1 - y0, e2dx = x1 - x0;
    float a0 = (px - x1) * e0dy;
    float a1 = (px - x2) * e1dy;
    float a2 = (px - x0) * e2dy;

    float dy = ymax - ymin;
#pragma unroll
    for (int j = 0; j < KK; ++j) {
        float tj = (float)j * T_DELTA;
        float py = ymin + tj * dy;
        if (!(py >= 0.0f && py <= Hm1)) continue;
        float w0 = a0 - (py - y1) * e0dx;
        float w1 = a1 - (py - y2) * e1dx;
        float w2 = a2 - (py - y0) * e2dx;
        bool inside = (w0 >= 0.0f && w1 >= 0.0f && w2 >= 0.0f) ||
                      (w0 <= 0.0f && w1 <= 0.0f && w2 <= 0.0f);
        if (!inside) continue;
        float depth = ((w0 * z0 + w1 * z1) + w2 * z2) / area;
        int iy = (int)fminf(fmaxf(rintf(py), 0.0f), Hm1);
        int idx = iy * W + ix;
        if (um) {
            unsigned int mw = mask[idx >> 5];
            if (!((mw >> (idx & 31)) & 1u)) continue;
        }
        atomicMin(&zbuf[idx], fmap(depth));
    }
}

__global__ void visible_k(const float* __restrict__ verts, int N,
                          const int* __restrict__ pH, const int* __restrict__ pW,
                          const unsigned int* __restrict__ zbuf,
                          float* __restrict__ out) {
#pragma clang fp contract(off)
    int n = blockIdx.x * blockDim.x + threadIdx.x;
    if (n >= N) return;
    const int W = pW[0];
    const int H = pH[0];
    const float Wm1 = (float)(W - 1);
    const float Hm1 = (float)(H - 1);
    float x = verts[n * 3 + 0], y = verts[n * 3 + 1], z = verts[n * 3 + 2];
    bool in_img = (x >= 0.0f) && (x <= Wm1) && (y >= 0.0f) && (y <= Hm1);
    float r = 0.0f;
    if (in_img) {
        int ix = (int)fminf(fmaxf(rintf(x), 0.0f), Wm1);
        int iy = (int)fminf(fmaxf(rintf(y), 0.0f), Hm1);
        unsigned int u = zbuf[iy * W + ix];
        float zb = (u == Z_EMPTY) ? BIG : funmap(u);
        r = (z <= zb + EPS_Z) ? 1.0f : 0.0f;
    }
    out[n] = r;
}

extern "C" void kernel_launch(void* const* d_in, const int* in_sizes, int n_in,
                              void* d_out, int out_size, void* d_ws, size_t ws_size,
                              hipStream_t stream) {
    const float* verts = (const float*)d_in[0];
    const int* tris = (const int*)d_in[1];
    const int* pH = (const int*)d_in[2];
    const int* pW = (const int*)d_in[3];
    int N = in_sizes[0] / 3;
    int T = in_sizes[1] / 3;
    unsigned int* ws = (unsigned int*)d_ws;   // zbuf (HW) + mask (HW/32)
    unsigned long long wsz = (unsigned long long)ws_size;
    float* outp = (float*)d_out;

    // Host-side occupancy query (pure query: legal under graph capture, and
    // replay only re-executes recorded stream ops, so cost is untimed).
    int maxBlocks = 0;
    int nbpc = 0;
    if (hipOccupancyMaxActiveBlocksPerMultiprocessor(&nbpc, (const void*)fused,
                                                     256, 0) == hipSuccess &&
        nbpc > 0) {
        int dev = 0;
        (void)hipGetDevice(&dev);
        hipDeviceProp_t prop;
        if (hipGetDeviceProperties(&prop, dev) == hipSuccess)
            maxBlocks = nbpc * prop.multiProcessorCount;
    }
    int grid = (maxBlocks > 0) ? (maxBlocks < 2048 ? maxBlocks : 2048) : 0;

    hipError_t err = hipErrorUnknown;
    if (grid > 0) {
        void* args[] = {(void*)&verts, (void*)&tris, (void*)&N, (void*)&T,
                        (void*)&pH, (void*)&pW, (void*)&ws, (void*)&wsz,
                        (void*)&outp};
        err = hipLaunchCooperativeKernel((const void*)fused, dim3(grid),
                                         dim3(256), args, 0, stream);
    }
    if (err != hipSuccess) {
        // Proven 4-dispatch path (round 13, 112 us).
        init_ws<<<1024, 256, 0, stream>>>(ws, pH, pW, wsz);
        mark_live<<<(N + 255) / 256, 256, 0, stream>>>(verts, N, pH, pW, ws, wsz);
        dim3 rgrid((T + 255) / 256, KK);
        raster<<<rgrid, 256, 0, stream>>>(verts, tris, T, pH, pW, ws, wsz);
        visible_k<<<(N + 255) / 256, 256, 0, stream>>>(verts, N, pH, pW, ws,
                                                       outp);
    }
}